// Round 2
// baseline (284.202 us; speedup 1.0000x reference)
//
#include <hip/hip_runtime.h>

// RBFolution: out[b,y,x,f] = exp(-beta[f] * (||patch||^2 - 2 patch.ccs[:,f] + ||ccs[:,f]||^2))
// x: [32,112,112,32] f32, ccs: [288,128] f32, beta: [128] f32
// out: [32,110,110,128] f32
//
// Strategy: implicit GEMM via bf16 MFMA (16x16x32). p_sq/c_sq kept fp32-exact;
// only the cross term is bf16 (error ~1e-5 << 2.3e-4 threshold).
// R1 fix: colsum row stride 112 on BOTH writer and reader (was 112 vs 130 mismatch
// -> garbage p_sq for taps i=1,2).

typedef __attribute__((ext_vector_type(8))) short bf16x8;
typedef __attribute__((ext_vector_type(4))) float f32x4;

#define HH 112
#define WW 112
#define CC 32
#define HO 110
#define WO 110
#define NF 128
#define KD 288          // 3*3*32
#define XPITCH 40       // LDS pixel pitch in bf16 elems (80B: 16B-aligned, 2-way bank alias only)

__device__ __forceinline__ unsigned short f32_to_bf16(float f) {
    unsigned u = __float_as_uint(f);
    unsigned r = u + 0x7FFFu + ((u >> 16) & 1u);   // round-to-nearest-even
    return (unsigned short)(r >> 16);
}

// --- Prologue: ccs [288][128] f32  ->  ccs_t [128][288] bf16 ; c_sq[f] = sum_d ccs[d][f]^2 (f32)
__global__ __launch_bounds__(256) void rbf_prologue(const float* __restrict__ ccs,
                                                    unsigned short* __restrict__ ccs_t,
                                                    float* __restrict__ c_sq) {
    int idx = blockIdx.x * 256 + threadIdx.x;     // 0..36863, coalesced read
    int d = idx >> 7;
    int f = idx & 127;
    float v = ccs[idx];
    ccs_t[f * KD + d] = f32_to_bf16(v);
    atomicAdd(&c_sq[f], v * v);
}

// --- Main: one block per (y, b). M-tile = 112 pixels (7 x 16), N = 128 filters.
__global__ __launch_bounds__(256) void rbf_main(const float* __restrict__ x,
                                                const unsigned short* __restrict__ ccs_t,
                                                const float* __restrict__ c_sq,
                                                const float* __restrict__ beta,
                                                float* __restrict__ out) {
    __shared__ unsigned short xs[3 * 130 * XPITCH];   // 3 rows x 130 px x 40 (32 ch + pad) bf16
    __shared__ float colsum[3 * 112 + 8];              // per (row i, col) sum of x^2 over 32 ch, stride 112
    __shared__ float p_sq[128];

    const int t = threadIdx.x;
    const int y = blockIdx.x;   // 0..109
    const int b = blockIdx.y;   // 0..31

    const float* xrow = x + (size_t)((b * HH + y) * WW) * CC;

    // Stage x[y..y+2][0..111][0..31] -> LDS bf16, and accumulate colsum from fp32.
    // 2688 float4 units: idx -> (i row, col, q quarter-of-channels)
    #pragma unroll
    for (int p = 0; p < 11; ++p) {
        int idx = t + p * 256;
        if (idx < 2688) {
            int q = idx & 7;
            int ic = idx >> 3;            // 0..335 = i*112 + col
            int col = ic % 112;
            int i = ic / 112;
            const float4 v = *(const float4*)(xrow + (i * WW + col) * CC + q * 4);
            unsigned short h0 = f32_to_bf16(v.x), h1 = f32_to_bf16(v.y);
            unsigned short h2 = f32_to_bf16(v.z), h3 = f32_to_bf16(v.w);
            uint2 pk;
            pk.x = (unsigned)h0 | ((unsigned)h1 << 16);
            pk.y = (unsigned)h2 | ((unsigned)h3 << 16);
            *(uint2*)(&xs[(i * 130 + col) * XPITCH + q * 4]) = pk;
            float part = v.x * v.x + v.y * v.y + v.z * v.z + v.w * v.w;
            part += __shfl_xor(part, 1);
            part += __shfl_xor(part, 2);
            part += __shfl_xor(part, 4);
            if (q == 0) colsum[ic] = part;   // ic = i*112 + col  (stride 112)
        }
    }
    __syncthreads();

    if (t < 112) {
        float s = 0.f;
        #pragma unroll
        for (int i = 0; i < 3; ++i)
            #pragma unroll
            for (int j = 0; j < 3; ++j)
                s += colsum[i * 112 + t + j];   // t+j <= 113: cols 112/113 read in-bounds garbage,
                                                 // but only feed p_sq[110..111] -> masked outputs
        p_sq[t] = s;
    }
    __syncthreads();

    // MFMA GEMM: A = patches [112 x 288] (from xs), B = ccs_t^T chunks [288 x 128]
    const int lane  = t & 63;
    const int wave  = t >> 6;            // 4 waves, each owns 32 filters
    const int laneM = lane & 15;
    const int quad  = lane >> 4;

    const int n0 = wave * 32 + laneM;    // filter for B-frag / C col, tile 0
    const int n1 = n0 + 16;              // tile 1
    const float csq0 = c_sq[n0], csq1 = c_sq[n1];
    const float bt0  = beta[n0], bt1  = beta[n1];

    f32x4 acc[7][2];
    #pragma unroll
    for (int mi = 0; mi < 7; ++mi) {
        acc[mi][0] = (f32x4){0.f, 0.f, 0.f, 0.f};
        acc[mi][1] = (f32x4){0.f, 0.f, 0.f, 0.f};
    }

    const unsigned short* bp0 = ccs_t + n0 * KD + quad * 8;
    const unsigned short* bp1 = ccs_t + n1 * KD + quad * 8;

    #pragma unroll
    for (int kb = 0; kb < 9; ++kb) {     // one k-block per (i,j) tap, K=32 channels
        const int ki = kb / 3, kj = kb % 3;
        bf16x8 b0 = *(const bf16x8*)(bp0 + kb * 32);   // B[k=kb*32+quad*8+j][n0]
        bf16x8 b1 = *(const bf16x8*)(bp1 + kb * 32);
        #pragma unroll
        for (int mi = 0; mi < 7; ++mi) {
            // A[m = mi*16+laneM][k] = x[y+ki][m+kj][quad*8..+7]
            const bf16x8 a = *(const bf16x8*)(&xs[(ki * 130 + mi * 16 + laneM + kj) * XPITCH + quad * 8]);
            acc[mi][0] = __builtin_amdgcn_mfma_f32_16x16x32_bf16(a, b0, acc[mi][0], 0, 0, 0);
            acc[mi][1] = __builtin_amdgcn_mfma_f32_16x16x32_bf16(a, b1, acc[mi][1], 0, 0, 0);
        }
    }

    // Epilogue: C layout col=lane&15 (filter), row=quad*4+r (pixel)
    float* orow = out + (size_t)((b * HO + y) * WO) * NF;
    #pragma unroll
    for (int mi = 0; mi < 7; ++mi) {
        #pragma unroll
        for (int r = 0; r < 4; ++r) {
            int m = mi * 16 + quad * 4 + r;
            if (m < WO) {
                float ps = p_sq[m];
                float s0 = ps - 2.f * acc[mi][0][r] + csq0;
                float s1 = ps - 2.f * acc[mi][1][r] + csq1;
                orow[(size_t)m * NF + n0] = __expf(-bt0 * s0);
                orow[(size_t)m * NF + n1] = __expf(-bt1 * s1);
            }
        }
    }
}

extern "C" void kernel_launch(void* const* d_in, const int* in_sizes, int n_in,
                              void* d_out, int out_size, void* d_ws, size_t ws_size,
                              hipStream_t stream) {
    const float* x    = (const float*)d_in[0];
    const float* ccs  = (const float*)d_in[1];
    const float* beta = (const float*)d_in[2];
    float* out = (float*)d_out;

    unsigned short* ccs_t = (unsigned short*)d_ws;                 // 128*288 bf16 = 73728 B
    float* c_sq = (float*)((char*)d_ws + 128 * KD * sizeof(unsigned short)); // 128 f32

    hipMemsetAsync(c_sq, 0, NF * sizeof(float), stream);
    rbf_prologue<<<144, 256, 0, stream>>>(ccs, ccs_t, c_sq);
    rbf_main<<<dim3(HO, 32), 256, 0, stream>>>(x, ccs_t, c_sq, beta, out);
}